// Round 4
// baseline (3126.375 us; speedup 1.0000x reference)
//
#include <hip/hip_runtime.h>

// ---------------------------------------------------------------------------
// GLIFR RSNN on MI355X — round 9: PLAIN-LAUNCH + TAGGED 64-bit DATA-IS-FLAG.
//
// History:
//   r1 (PASSED, 11.75ms): 8 WGs/batch, cooperative, counter barrier.
//   r2/r3/r4/r7 (GHOST): cooperative launch + modified sync machinery ->
//      kernel never ran (r7: quick return, even slabs zero -> launch/graph
//      rejected, NOT a hang/race). Plain launches have never ghosted.
//   r5 (PASSED, 2290us recur): counter protocol = 4 serial L3 RTTs/step
//      (~4600cy) + compute (~850cy) = 5500cy/step. VALUBusy 23%, HBM 4%.
//   r6 (REGRESSED): no slack to hide work in; chain is pure serial RTTs.
//   r8 (DIED): VGPR math error — 8x64 weights = 512 VGPR/thread, not 128.
//      Lesson: one CU's regfile holds only half of Wr; cross-CU exchange is
//      irreducible. Optimize exchange LATENCY.
//   r9 (this): r5's compute verbatim; exchange via 2-slot ping-pong of
//      64-bit words {tag=t+1 | fp32 bits} stored with ONE relaxed agent
//      atomic each. Consumer polls the word itself: detect+data in one load
//      (~1.5-2 RTT vs counter protocol's ~4). No drain, no fetch_add, no
//      counter spin, no memset, NO COOPERATIVE LAUNCH (plain 256 WGs on 256
//      CUs; resources allow 2 WGs/CU so residency is robust; bounded polls
//      with a give-up flag make worst case a fast visible failure, never a
//      hang).
//      Safety proofs:
//        - ping-pong overwrite: producing spb_t requires having consumed all
//          spb_{t-1}; its producers consumed spb_{t-2} (program order) ->
//          slot t&1 (holding spb_{t-2}) is dead before overwrite.
//        - stale tags (prev run / timing replays): each slot slice is
//          overwritten at its owner's t=0/t=1, which dependence-precedes any
//          poll that could match a stale tag (t=999) -> self-cleaning.
//        - ws poison 0xAA: hi32=0xAAAAAAAA != any tag in [1,1000].
//
// NOTE (r2/r3 lesson, keep): fp32 S is EXACTLY 0.0 for strongly inhibited
// neurons (V ~ -1050 -> __expf overflow -> 20/inf = 0), identically in the
// jax reference. 0x00000000 output words are legitimate.
// ---------------------------------------------------------------------------

#define T_STEPS 1000
#define NB 32
#define N0 256
#define N1 512

// fp32 constants, folded exactly like the reference's python-float scalars
#define C_SYN_D 0.95f                      // 1 - DT*KSYN
#define C_SYN_I 0.05f                      // DT*KSYN
#define C_V_D   0.99f                      // 1 - DT*KM
#define C_KMR   0.0010604453870625663f     // DT*KM*R
#define C_TH    10.986122886681098f        // SIGMA_V * log((20-5)/5)
#define C_A0_D  0.99985f                   // 1 - DT*0.003
#define C_A0_I  (-0.459f)                  // -9.18*1.0*DT
#define C_A1_D  0.995f                     // 1 - DT*0.1
#define C_A1_I  (-9.947f)                  // -198.94*1.0*DT

__device__ __forceinline__ float glif_S(float V) {
  // 20 * sigmoid((V - TH)/10)
  return 20.0f / (1.0f + __expf((C_TH - V) * 0.1f));
}

// ---------------------------------------------------------------------------
// Kernel A: layer-0 scan (r5-verbatim, proven). grid = 128 x 64.
// ---------------------------------------------------------------------------
__global__ __launch_bounds__(64)
void layer0_scan(const float* __restrict__ x, float* __restrict__ S0) {
  const int g = blockIdx.x * 64 + threadIdx.x;
  float V = 0.f, a0 = 0.f, a1 = 0.f, Is = 0.f;
  float xb[8];
#pragma unroll
  for (int i = 0; i < 8; ++i) xb[i] = x[i * (NB * N0) + g];
#pragma unroll 1
  for (int tb = 0; tb < T_STEPS / 8; ++tb) {
#pragma unroll
    for (int u = 0; u < 8; ++u) {
      const int t = tb * 8 + u;
      const float xi = xb[u];
      const int tf = t + 8;
      if (tf < T_STEPS) xb[u] = x[tf * (NB * N0) + g];
      Is = fmaf(Is, C_SYN_D, C_SYN_I * xi);
      V  = fmaf(V, C_V_D, C_KMR * (Is + a0 + a1));
      const float S = glif_S(V);
      a0 = fmaf(a0, C_A0_D, C_A0_I * S);
      a1 = fmaf(a1, C_A1_D, C_A1_I * S);
      S0[t * (NB * N0) + g] = S;
    }
  }
}

// ---------------------------------------------------------------------------
// Kernel C: recurrence. grid = 256 x 256, PLAIN launch.
// wg = b*8 + s; m-slice = [s*64, s*64+64). tid = mg*16 + kc (r5-identical).
// Exchange: xch[slot][b][n] as uint64 {tag<<32 | bits}; spb_t -> slot t&1,
// tag t+1. Consumer at step t polls slot (t-1)&1 for hi32 == t.
// ---------------------------------------------------------------------------
__global__ __launch_bounds__(256, 1)
void rsnn_recur(const float* __restrict__ W1, const float* __restrict__ Wr,
                const float* __restrict__ S0, float* __restrict__ out,
                unsigned long long* __restrict__ xch) {
  const int wg  = blockIdx.x;
  const int b   = wg >> 3;
  const int s   = wg & 7;
  const int tid = threadIdx.x;
  const int mg  = tid >> 4;
  const int kc  = tid & 15;
  const int mBase = s * 64 + mg * 4;

  __shared__ float actS[16 * 36];   // 512 spb values, padded (r5 layout)
  __shared__ float actO[16 * 20];   // 256 S0 values, padded (r5 layout)

  // --- one-time weight load into registers (r5-verbatim) ---
  float4 wr4[4][8];
  float4 w14[4][4];
#pragma unroll
  for (int i = 0; i < 4; ++i) {
    const float4* rw = (const float4*)(Wr + (size_t)(mBase + i) * N1 + kc * 32);
#pragma unroll
    for (int j = 0; j < 8; ++j) wr4[i][j] = rw[j];
    const float4* r1 = (const float4*)(W1 + (size_t)(mBase + i) * N0 + kc * 16);
#pragma unroll
    for (int j = 0; j < 4; ++j) w14[i][j] = r1[j];
  }

  float V[4]   = {0.f, 0.f, 0.f, 0.f};
  float A0v[4] = {0.f, 0.f, 0.f, 0.f};
  float A1v[4] = {0.f, 0.f, 0.f, 0.f};
  float Is[4]  = {0.f, 0.f, 0.f, 0.f};

  bool gave_up = false;   // safety: after one poll cap, never block again

#pragma unroll 1
  for (int t = 0; t < T_STEPS; ++t) {
    // ---- stage previous activations into LDS ----
    if (t == 0) {
      actS[(tid >> 5) * 36 + (tid & 31)] = 0.f;
      {
        const int k = tid + 256;
        actS[(k >> 5) * 36 + (k & 31)] = 0.f;
      }
      actO[(tid >> 4) * 20 + (tid & 15)] = 0.f;
    } else {
      // issue the (plain, cached) S0 load first so it flies under the poll
      const float v2 = S0[(size_t)(t - 1) * (NB * N0) + b * N0 + tid];
      const unsigned long long* px =
          xch + (size_t)((t - 1) & 1) * (NB * N1) + (size_t)b * N1;
      const unsigned tg = (unsigned)t;     // tag of spb_{t-1}
      unsigned long long w0 = 0ull, w1 = 0ull;
      bool r0 = false, r1 = false;
      int iter = gave_up ? (1 << 30) : 0;
      for (;;) {
        if (!r0) {
          w0 = __hip_atomic_load(px + tid, __ATOMIC_RELAXED,
                                 __HIP_MEMORY_SCOPE_AGENT);
          r0 = ((unsigned)(w0 >> 32) == tg);
        }
        if (!r1) {
          w1 = __hip_atomic_load(px + tid + 256, __ATOMIC_RELAXED,
                                 __HIP_MEMORY_SCOPE_AGENT);
          r1 = ((unsigned)(w1 >> 32) == tg);
        }
        if (r0 && r1) break;
        if (++iter > (1 << 17)) { gave_up = true; break; }  // ~ms, visible fail
        __builtin_amdgcn_s_sleep(1);   // throttle fabric pressure
      }
      actS[(tid >> 5) * 36 + (tid & 31)] = __uint_as_float((unsigned)w0);
      {
        const int k = tid + 256;
        actS[(k >> 5) * 36 + (k & 31)] = __uint_as_float((unsigned)w1);
      }
      actO[(tid >> 4) * 20 + (tid & 15)] = v2;
    }
    __syncthreads();  // staging visible

    // ---- partial dot products (r5-verbatim) ----
    float h2a[4] = {0.f, 0.f, 0.f, 0.f};
    float h1a[4] = {0.f, 0.f, 0.f, 0.f};
    const float4* aS4 = (const float4*)actS;
    const float4* aO4 = (const float4*)actO;
#pragma unroll
    for (int j = 0; j < 8; ++j) {
      const float4 a = aS4[kc * 9 + j];
#pragma unroll
      for (int i = 0; i < 4; ++i) {
        h2a[i] = fmaf(wr4[i][j].x, a.x, h2a[i]);
        h2a[i] = fmaf(wr4[i][j].y, a.y, h2a[i]);
        h2a[i] = fmaf(wr4[i][j].z, a.z, h2a[i]);
        h2a[i] = fmaf(wr4[i][j].w, a.w, h2a[i]);
      }
    }
#pragma unroll
    for (int j = 0; j < 4; ++j) {
      const float4 a = aO4[kc * 5 + j];
#pragma unroll
      for (int i = 0; i < 4; ++i) {
        h1a[i] = fmaf(w14[i][j].x, a.x, h1a[i]);
        h1a[i] = fmaf(w14[i][j].y, a.y, h1a[i]);
        h1a[i] = fmaf(w14[i][j].z, a.z, h1a[i]);
        h1a[i] = fmaf(w14[i][j].w, a.w, h1a[i]);
      }
    }
    __syncthreads();  // all LDS reads done; next iteration may overwrite

    // ---- reduce across the 16 k-chunks (r5-verbatim order) ----
#pragma unroll
    for (int mask = 1; mask <= 8; mask <<= 1) {
#pragma unroll
      for (int i = 0; i < 4; ++i) {
        h2a[i] += __shfl_xor(h2a[i], mask, 64);
        h1a[i] += __shfl_xor(h1a[i], mask, 64);
      }
    }

    // ---- owner lanes: GLIF A (h1) then GLIF B (h2) — r5-verbatim math ----
    if (kc == 0) {
      float spa[4], spb[4];
#pragma unroll
      for (int i = 0; i < 4; ++i) {
        Is[i] = fmaf(Is[i], C_SYN_D, C_SYN_I * h1a[i]);
        V[i]  = fmaf(V[i], C_V_D, C_KMR * (Is[i] + A0v[i] + A1v[i]));
        const float Sa = glif_S(V[i]);
        A0v[i] = fmaf(A0v[i], C_A0_D, C_A0_I * Sa);
        A1v[i] = fmaf(A1v[i], C_A1_D, C_A1_I * Sa);
        spa[i] = Sa;
        Is[i] = fmaf(Is[i], C_SYN_D, C_SYN_I * h2a[i]);
        V[i]  = fmaf(V[i], C_V_D, C_KMR * (Is[i] + A0v[i] + A1v[i]));
        const float Sb = glif_S(V[i]);
        A0v[i] = fmaf(A0v[i], C_A0_D, C_A0_I * Sb);
        A1v[i] = fmaf(A1v[i], C_A1_D, C_A1_I * Sb);
        spb[i] = Sb;
      }
      // plain output stores — nobody reads out during the kernel anymore
      float* outA = out + ((size_t)(2 * t) * NB + b) * N1 + mBase;
      *(float4*)outA = make_float4(spa[0], spa[1], spa[2], spa[3]);
      float* outB = out + ((size_t)(2 * t + 1) * NB + b) * N1 + mBase;
      *(float4*)outB = make_float4(spb[0], spb[1], spb[2], spb[3]);

      // tagged exchange stores: one 8B relaxed agent atomic per neuron.
      // tag = t+1; slot = t&1. No drain, no flag, no barrier needed.
      unsigned long long* qx =
          xch + (size_t)(t & 1) * (NB * N1) + (size_t)b * N1 + mBase;
      const unsigned long long tg1 = ((unsigned long long)(t + 1)) << 32;
#pragma unroll
      for (int i = 0; i < 4; ++i)
        __hip_atomic_store(qx + i,
                           tg1 | (unsigned long long)__float_as_uint(spb[i]),
                           __ATOMIC_RELAXED, __HIP_MEMORY_SCOPE_AGENT);
    }
    // no arrive machinery: the tagged stores ARE the readiness signal.
  }
}

// ---------------------------------------------------------------------------
extern "C" void kernel_launch(void* const* d_in, const int* in_sizes, int n_in,
                              void* d_out, int out_size, void* d_ws, size_t ws_size,
                              hipStream_t stream) {
  const float* inputs = (const float*)d_in[0];   // [1000,32,1,256]
  const float* W1     = (const float*)d_in[1];   // [512,256]
  const float* Wr     = (const float*)d_in[2];   // [512,512]
  float* out = (float*)d_out;                    // [2000,32,1,512]

  float* S0 = (float*)d_ws;                      // 32,768,000 B (as r5)
  // tagged ping-pong exchange: 2 slots x 32 b x 512 n x 8B = 262,144 B,
  // 8B-aligned right after S0. Self-cleaning (tags), no memset required.
  unsigned long long* xch = (unsigned long long*)((char*)d_ws +
                              (size_t)T_STEPS * NB * N0 * sizeof(float));

  hipLaunchKernelGGL(layer0_scan, dim3((NB * N0) / 64), dim3(64), 0, stream,
                     inputs, S0);
  // PLAIN launch: 256 WGs on 256 CUs; each CU has headroom for 2 such WGs
  // (3584B LDS, <=256 VGPR), so full residency is robust; bounded polls
  // guarantee termination regardless.
  hipLaunchKernelGGL(rsnn_recur, dim3(256), dim3(256), 0, stream,
                     W1, Wr, S0, out, xch);
}